// Round 6
// baseline (750.456 us; speedup 1.0000x reference)
//
#include <hip/hip_runtime.h>

#define NPTS 294912
#define CDIM 128
#define HH 8
#define KPATCH 48
#define DD 16
#define NP (NPTS / KPATCH)      // 6144 patches
#define POS_BND 11
#define RPE_NUM 23
#define RPE_ROWS (3 * RPE_NUM)  // 69
#define QSCALE 0.25f
#define QKVC 384                // 3*C cols
#define QKVB 768                // bf16 row bytes

typedef __attribute__((ext_vector_type(8))) short short8v;  // 8 bf16
typedef __attribute__((ext_vector_type(4))) short short4v;  // 4 bf16
typedef __attribute__((ext_vector_type(4))) float f32x4;
typedef __attribute__((ext_vector_type(4))) float f4v;

__device__ __forceinline__ unsigned short bf16r(float x) {   // RNE bf16
    unsigned u = __float_as_uint(x);
    return (unsigned short)((u + 0x7fffu + ((u >> 16) & 1u)) >> 16);
}

__device__ __forceinline__ void split8(const float* x, short8v& hi, short8v& lo) {
    #pragma unroll
    for (int i = 0; i < 8; ++i) {
        unsigned u = __float_as_uint(x[i]);
        hi[i] = (short)(u >> 16);
        float l = x[i] - __uint_as_float(u & 0xffff0000u);
        lo[i] = (short)(__float_as_uint(l) >> 16);
    }
}

__device__ __forceinline__ void round8(const float* x, short8v& hi) {
    #pragma unroll
    for (int i = 0; i < 8; ++i) hi[i] = (short)bf16r(x[i]);
}

// ================= K1: QKV GEMM, linear in / linear bf16 out =================
// 64 source rows per block. qkv_ws[i][c] bf16, c in [0,384): q|k|v, bias+scale applied.
#define K1ROWS 64
#define K1_LDS 49152   // max(featH+featL = 32768, stage 64*768 = 49152)

__global__ __launch_bounds__(256, 3) void k1_qkv(
    const float* __restrict__ feat,
    const float* __restrict__ w_qkv,
    const float* __restrict__ b_qkv,
    unsigned short* __restrict__ qkv_ws)
{
    __shared__ __align__(16) char uni[K1_LDS];

    const int tid  = threadIdx.x;
    const int wid  = tid >> 6;
    const int lane = tid & 63;
    const int lrow = lane & 15;
    const int lgrp = lane >> 4;
    const size_t rbase = (size_t)blockIdx.x * K1ROWS;

    // ---- linear load 64x128 feat -> split bf16 hi/lo (XOR swizzle) ----
    #pragma unroll
    for (int it = 0; it < 4; ++it) {
        int e  = tid + it * 256;
        int r  = e >> 4;
        int c8 = e & 15;
        const float* src = feat + (rbase + r) * CDIM + c8 * 8;
        float x[8];
        *(f4v*)(x)     = __builtin_nontemporal_load((const f4v*)src);
        *(f4v*)(x + 4) = __builtin_nontemporal_load((const f4v*)(src + 4));
        short8v hi, lo;
        split8(x, hi, lo);
        int addr = (r * 256 + c8 * 16) ^ ((r & 7) << 4);
        *(short8v*)(uni + addr)         = hi;
        *(short8v*)(uni + 16384 + addr) = lo;
    }
    __syncthreads();

    // ---- GEMM M=64 N=384 K=128: split-A x single-B ----
    f32x4 acc[4][6];
    #pragma unroll
    for (int i = 0; i < 4; ++i)
        #pragma unroll
        for (int j = 0; j < 6; ++j) acc[i][j] = (f32x4)0.0f;

    #pragma unroll
    for (int ks = 0; ks < 4; ++ks) {
        short8v aH[4], aL[4];
        #pragma unroll
        for (int mt = 0; mt < 4; ++mt) {
            int row  = mt * 16 + lrow;
            int boff = (row * 256 + ks * 64 + lgrp * 16) ^ ((row & 7) << 4);
            aH[mt] = *(const short8v*)(uni + boff);
            aL[mt] = *(const short8v*)(uni + 16384 + boff);
        }
        #pragma unroll
        for (int nt = 0; nt < 6; ++nt) {
            int NT = wid * 6 + nt;
            const float* wp = w_qkv + (size_t)(NT * 16 + lrow) * CDIM + ks * 32 + lgrp * 8;
            float x[8];
            *(float4*)(x)     = *(const float4*)wp;
            *(float4*)(x + 4) = *(const float4*)(wp + 4);
            short8v bH;
            round8(x, bH);
            #pragma unroll
            for (int mt = 0; mt < 4; ++mt) {
                acc[mt][nt] = __builtin_amdgcn_mfma_f32_16x16x32_bf16(aH[mt], bH, acc[mt][nt], 0, 0, 0);
                acc[mt][nt] = __builtin_amdgcn_mfma_f32_16x16x32_bf16(aL[mt], bH, acc[mt][nt], 0, 0, 0);
            }
        }
    }
    __syncthreads();   // feat reads done; region becomes bf16 stage [64][768B]

    // ---- epilogue: bias (+scale for q), bf16, stage rows (XOR'd 16B units) ----
    #pragma unroll
    for (int nt = 0; nt < 6; ++nt) {
        int NT  = wid * 6 + nt;
        int col = NT * 16 + lrow;
        float bq = b_qkv[col];
        float scale = (col < CDIM) ? QSCALE : 1.0f;
        #pragma unroll
        for (int mt = 0; mt < 4; ++mt)
            #pragma unroll
            for (int r = 0; r < 4; ++r) {
                int row = mt * 16 + lgrp * 4 + r;
                unsigned short b = bf16r((acc[mt][nt][r] + bq) * scale);
                int addr = row * QKVB + ((col * 2) ^ ((row & 7) << 4));
                *(unsigned short*)(uni + addr) = b;
            }
    }
    __syncthreads();

    // ---- linear row writes: 64 rows x 768 B ----
    #pragma unroll
    for (int it = 0; it < 12; ++it) {
        int e   = tid + it * 256;
        int r   = e / 48;
        int c16 = e - r * 48;
        int addr = r * QKVB + ((c16 * 16) ^ ((r & 7) << 4));
        short8v v = *(const short8v*)(uni + addr);
        *(short8v*)((char*)qkv_ws + (rbase + r) * QKVB + c16 * 16) = v;
    }
}

// ================= K2: per-patch attention + proj =================
// LDS union (36864 B): Q @0 [8][48][32B], K @12288, Vt @24576 [8][16][96B]
// then aoH @0 | aoL @12288 ; then fp32 out tile [48][132] @0
#define UNI_BYTES 36864
#define KOFF 12288
#define VOFF 24576
#define OTS 132

__global__ __launch_bounds__(256, 4) void k2_attn(
    const unsigned short* __restrict__ qkv_ws,
    const float* __restrict__ w_proj,
    const float* __restrict__ b_proj,
    const float* __restrict__ rpe,
    const int* __restrict__ order,
    const int* __restrict__ grid_coord,
    float* __restrict__ dst,     // mode0: out (scatter by ord), mode1: ws2 linear
    int mode)
{
    __shared__ int ord[KPATCH];
    __shared__ int gcl[KPATCH][3];
    __shared__ float rpe_l[RPE_ROWS * HH];
    __shared__ __align__(16) char uni[UNI_BYTES];

    const int p    = blockIdx.x;
    const int tid  = threadIdx.x;
    const int wid  = tid >> 6;
    const int lane = tid & 63;
    const int lrow = lane & 15;
    const int lgrp = lane >> 4;

    if (tid < KPATCH) {
        int o = order[p * KPATCH + tid];
        ord[tid] = o;
        gcl[tid][0] = grid_coord[o * 3 + 0];
        gcl[tid][1] = grid_coord[o * 3 + 1];
        gcl[tid][2] = grid_coord[o * 3 + 2];
    }
    for (int e = tid; e < RPE_ROWS * HH; e += 256) rpe_l[e] = rpe[e];
    __syncthreads();

    // ---- gather 48 qkv rows (768 B each), scatter into Q/K/Vt swizzled LDS ----
    #pragma unroll
    for (int it = 0; it < 9; ++it) {
        int e = tid + it * 256;
        if (e < KPATCH * 48) {
            int r   = e / 48;
            int c16 = e - r * 48;
            short8v v = *(const short8v*)((const char*)qkv_ws + (size_t)ord[r] * QKVB + c16 * 16);
            int c0   = c16 * 8;            // first col of chunk
            int type = c0 >> 7;            // 0=q 1=k 2=v
            int hh   = (c0 >> 4) & 7;
            int d0   = c0 & 15;            // 0 or 8
            if (type < 2) {
                int base = type * KOFF + hh * 1536 + r * 32;
                short4v g0 = { v[0], v[1], v[2], v[3] };
                short4v g1 = { v[4], v[5], v[6], v[7] };
                int u0 = ((((d0    ) >> 2) ^ (r >> 2)) & 3) * 8;
                int u1 = ((((d0 + 4) >> 2) ^ (r >> 2)) & 3) * 8;
                *(short4v*)(uni + base + u0) = g0;
                *(short4v*)(uni + base + u1) = g1;
            } else {
                int mb = r >> 2;
                #pragma unroll
                for (int j = 0; j < 8; ++j) {
                    int d = d0 + j;
                    int addr = VOFF + hh * 1536 + d * 96
                             + (((mb & ~3) | ((mb ^ (d >> 2)) & 3))) * 8 + (r & 3) * 2;
                    *(unsigned short*)(uni + addr) = (unsigned short)v[j];
                }
            }
        }
    }
    __syncthreads();

    // ---- MFMA attention: 2 heads per wave (identical to proven r4 code) ----
    f32x4 oall[2][3];
    #pragma unroll
    for (int ht = 0; ht < 2; ++ht) {
        const int h = wid * 2 + ht;
        short8v kf[3], qf[3];
        #pragma unroll
        for (int t = 0; t < 3; ++t) {
            int row = t * 16 + lrow;
            int ra  = row * 32 + (((lgrp ^ (row >> 2)) & 3)) * 8;
            short4v kq = *(const short4v*)(uni + KOFF + h * 1536 + ra);
            short4v qq = *(const short4v*)(uni +        h * 1536 + ra);
            short8v a, b;
            a[0]=kq[0]; a[1]=kq[1]; a[2]=kq[2]; a[3]=kq[3]; a[4]=0; a[5]=0; a[6]=0; a[7]=0;
            b[0]=qq[0]; b[1]=qq[1]; b[2]=qq[2]; b[3]=qq[3]; b[4]=0; b[5]=0; b[6]=0; b[7]=0;
            kf[t] = a; qf[t] = b;
        }
        f32x4 s[3][3];
        #pragma unroll
        for (int qt = 0; qt < 3; ++qt)
            #pragma unroll
            for (int mt = 0; mt < 3; ++mt)
                s[qt][mt] = __builtin_amdgcn_mfma_f32_16x16x32_bf16(kf[mt], qf[qt], (f32x4)0.0f, 0, 0, 0);

        #pragma unroll
        for (int qt = 0; qt < 3; ++qt) {
            int q  = qt * 16 + lrow;
            int gx = gcl[q][0], gy = gcl[q][1], gz = gcl[q][2];
            #pragma unroll
            for (int mt = 0; mt < 3; ++mt)
                #pragma unroll
                for (int r = 0; r < 4; ++r) {
                    int m  = mt * 16 + lgrp * 4 + r;
                    int rx = gx - gcl[m][0];
                    int ry = gy - gcl[m][1];
                    int rz = gz - gcl[m][2];
                    rx = rx < -POS_BND ? -POS_BND : (rx > POS_BND ? POS_BND : rx);
                    ry = ry < -POS_BND ? -POS_BND : (ry > POS_BND ? POS_BND : ry);
                    rz = rz < -POS_BND ? -POS_BND : (rz > POS_BND ? POS_BND : rz);
                    s[qt][mt][r] += rpe_l[(rx + POS_BND) * HH + h]
                                  + rpe_l[(ry + POS_BND + RPE_NUM) * HH + h]
                                  + rpe_l[(rz + POS_BND + 2 * RPE_NUM) * HH + h];
                }
        }

        #pragma unroll
        for (int qt = 0; qt < 3; ++qt) {
            float mx = -1e30f;
            #pragma unroll
            for (int mt = 0; mt < 3; ++mt)
                #pragma unroll
                for (int r = 0; r < 4; ++r) mx = fmaxf(mx, s[qt][mt][r]);
            mx = fmaxf(mx, __shfl_xor(mx, 16));
            mx = fmaxf(mx, __shfl_xor(mx, 32));
            float sum = 0.f;
            #pragma unroll
            for (int mt = 0; mt < 3; ++mt)
                #pragma unroll
                for (int r = 0; r < 4; ++r) {
                    float e = __expf(s[qt][mt][r] - mx);
                    s[qt][mt][r] = e;
                    sum += e;
                }
            sum += __shfl_xor(sum, 16);
            sum += __shfl_xor(sum, 32);
            float inv = 1.0f / sum;
            #pragma unroll
            for (int mt = 0; mt < 3; ++mt)
                #pragma unroll
                for (int r = 0; r < 4; ++r) s[qt][mt][r] *= inv;
        }

        short8v vb0, vb1;
        {
            int base = VOFF + h * 1536 + lrow * 96 + (((lgrp ^ (lrow >> 2)) & 3)) * 8;
            short4v x0 = *(const short4v*)(uni + base);
            short4v x1 = *(const short4v*)(uni + base + 32);
            short4v x2 = *(const short4v*)(uni + base + 64);
            vb0[0]=x0[0]; vb0[1]=x0[1]; vb0[2]=x0[2]; vb0[3]=x0[3];
            vb0[4]=x1[0]; vb0[5]=x1[1]; vb0[6]=x1[2]; vb0[7]=x1[3];
            vb1[0]=x2[0]; vb1[1]=x2[1]; vb1[2]=x2[2]; vb1[3]=x2[3];
            vb1[4]=0; vb1[5]=0; vb1[6]=0; vb1[7]=0;
        }
        #pragma unroll
        for (int qt = 0; qt < 3; ++qt) {
            short8v pa0, pa1;
            #pragma unroll
            for (int j = 0; j < 4; ++j) {
                pa0[j]     = (short)bf16r(s[qt][0][j]);
                pa0[4 + j] = (short)bf16r(s[qt][1][j]);
                pa1[j]     = (short)bf16r(s[qt][2][j]);
                pa1[4 + j] = 0;
            }
            f32x4 o = __builtin_amdgcn_mfma_f32_16x16x32_bf16(pa0, vb0, (f32x4)0.0f, 0, 0, 0);
            o = __builtin_amdgcn_mfma_f32_16x16x32_bf16(pa1, vb1, o, 0, 0, 0);
            oall[ht][qt] = o;
        }
    }
    __syncthreads();   // qkv reads done; region becomes aoH/aoL

    // ---- write attention output hi/lo bf16 tile ----
    #pragma unroll
    for (int ht = 0; ht < 2; ++ht) {
        int c = (wid * 2 + ht) * 16 + lrow;
        #pragma unroll
        for (int qt = 0; qt < 3; ++qt)
            #pragma unroll
            for (int r = 0; r < 4; ++r) {
                int q = qt * 16 + lgrp * 4 + r;
                float x = oall[ht][qt][r];
                unsigned u = __float_as_uint(x);
                unsigned short h16 = (unsigned short)(u >> 16);
                float lres = x - __uint_as_float(u & 0xffff0000u);
                unsigned short l16 = (unsigned short)(__float_as_uint(lres) >> 16);
                int addr = (q * 256 + c * 2) ^ ((q & 7) << 4);
                *(unsigned short*)(uni + addr)        = h16;
                *(unsigned short*)(uni + KOFF + addr) = l16;
            }
    }
    __syncthreads();

    // ---- proj GEMM (split-A x split-B, identical to r5) ----
    f32x4 pacc[3][2];
    #pragma unroll
    for (int i = 0; i < 3; ++i)
        #pragma unroll
        for (int j = 0; j < 2; ++j) pacc[i][j] = (f32x4)0.0f;

    #pragma unroll
    for (int ks = 0; ks < 4; ++ks) {
        short8v aH[3], aL[3];
        #pragma unroll
        for (int mt = 0; mt < 3; ++mt) {
            int row  = mt * 16 + lrow;
            int boff = (row * 256 + ks * 64 + lgrp * 16) ^ ((row & 7) << 4);
            aH[mt] = *(const short8v*)(uni + boff);
            aL[mt] = *(const short8v*)(uni + KOFF + boff);
        }
        #pragma unroll
        for (int nt = 0; nt < 2; ++nt) {
            int NT = wid * 2 + nt;
            const float* wp = w_proj + (size_t)(NT * 16 + lrow) * CDIM + ks * 32 + lgrp * 8;
            float x[8];
            *(float4*)(x)     = *(const float4*)wp;
            *(float4*)(x + 4) = *(const float4*)(wp + 4);
            short8v bH, bL;
            split8(x, bH, bL);
            #pragma unroll
            for (int mt = 0; mt < 3; ++mt) {
                pacc[mt][nt] = __builtin_amdgcn_mfma_f32_16x16x32_bf16(aH[mt], bH, pacc[mt][nt], 0, 0, 0);
                pacc[mt][nt] = __builtin_amdgcn_mfma_f32_16x16x32_bf16(aL[mt], bH, pacc[mt][nt], 0, 0, 0);
                pacc[mt][nt] = __builtin_amdgcn_mfma_f32_16x16x32_bf16(aH[mt], bL, pacc[mt][nt], 0, 0, 0);
            }
        }
    }
    __syncthreads();   // proj LDS reads done; region becomes fp32 out tile

    float* ot = (float*)uni;
    #pragma unroll
    for (int nt = 0; nt < 2; ++nt) {
        int NT = wid * 2 + nt;
        int c  = NT * 16 + lrow;
        float bp = b_proj[c];
        #pragma unroll
        for (int mt = 0; mt < 3; ++mt)
            #pragma unroll
            for (int r = 0; r < 4; ++r) {
                int row = mt * 16 + lgrp * 4 + r;
                ot[row * OTS + c] = pacc[mt][nt][r] + bp;
            }
    }
    __syncthreads();

    #pragma unroll
    for (int it = 0; it < 6; ++it) {
        int e  = tid + it * 256;
        int r  = e >> 5;
        int c4 = e & 31;
        f4v v = *(const f4v*)&ot[r * OTS + c4 * 4];
        size_t row = (mode == 0) ? (size_t)ord[r] : ((size_t)p * KPATCH + r);
        *(f4v*)(dst + row * CDIM + c4 * 4) = v;
    }
}

// ================= K3: permutation copy, gathered read / linear write =================
__global__ __launch_bounds__(256, 8) void k3_perm(
    const float* __restrict__ ws2,
    const int* __restrict__ inverse,
    float* __restrict__ out)
{
    __shared__ int ip[64];
    const int tid = threadIdx.x;
    const size_t j0 = (size_t)blockIdx.x * 64;
    if (tid < 64) ip[tid] = inverse[j0 + tid];
    __syncthreads();
    #pragma unroll
    for (int it = 0; it < 8; ++it) {
        int e  = tid + it * 256;
        int r  = e >> 5;
        int c4 = e & 31;
        f4v v = *(const f4v*)(ws2 + (size_t)ip[r] * CDIM + c4 * 4);
        __builtin_nontemporal_store(v, (f4v*)(out + (j0 + r) * CDIM + c4 * 4));
    }
}

// ================= Fallback: r5 fused kernel (used only if ws too small) =================
#define FS 132
__global__ __launch_bounds__(256, 4) void fused_patch_attn(
    const float* __restrict__ feat,
    const float* __restrict__ w_qkv,
    const float* __restrict__ b_qkv,
    const float* __restrict__ w_proj,
    const float* __restrict__ b_proj,
    const float* __restrict__ rpe,
    const int* __restrict__ order,
    const int* __restrict__ grid_coord,
    float* __restrict__ out)
{
    __shared__ int ord[KPATCH];
    __shared__ int gcl[KPATCH][3];
    __shared__ float rpe_l[RPE_ROWS * HH];
    __shared__ __align__(16) char uni[UNI_BYTES];

    const int p    = blockIdx.x;
    const int tid  = threadIdx.x;
    const int wid  = tid >> 6;
    const int lane = tid & 63;
    const int lrow = lane & 15;
    const int lgrp = lane >> 4;

    if (tid < KPATCH) {
        int o = order[p * KPATCH + tid];
        ord[tid] = o;
        gcl[tid][0] = grid_coord[o * 3 + 0];
        gcl[tid][1] = grid_coord[o * 3 + 1];
        gcl[tid][2] = grid_coord[o * 3 + 2];
    }
    for (int e = tid; e < RPE_ROWS * HH; e += 256) rpe_l[e] = rpe[e];
    __syncthreads();

    for (int e = tid; e < KPATCH * 16; e += 256) {
        int r  = e >> 4;
        int c8 = e & 15;
        const float* src = feat + (size_t)ord[r] * CDIM + c8 * 8;
        float x[8];
        *(f4v*)(x)     = __builtin_nontemporal_load((const f4v*)src);
        *(f4v*)(x + 4) = __builtin_nontemporal_load((const f4v*)(src + 4));
        short8v hi, lo;
        split8(x, hi, lo);
        int addr = (r * 256 + c8 * 16) ^ ((r & 7) << 4);
        *(short8v*)(uni + addr)        = hi;
        *(short8v*)(uni + KOFF + addr) = lo;
    }
    __syncthreads();

    f32x4 acc[3][6];
    #pragma unroll
    for (int i = 0; i < 3; ++i)
        #pragma unroll
        for (int j = 0; j < 6; ++j) acc[i][j] = (f32x4)0.0f;

    #pragma unroll
    for (int ks = 0; ks < 4; ++ks) {
        short8v aH[3], aL[3];
        #pragma unroll
        for (int mt = 0; mt < 3; ++mt) {
            int row  = mt * 16 + lrow;
            int boff = (row * 256 + ks * 64 + lgrp * 16) ^ ((row & 7) << 4);
            aH[mt] = *(const short8v*)(uni + boff);
            aL[mt] = *(const short8v*)(uni + KOFF + boff);
        }
        #pragma unroll
        for (int nt = 0; nt < 6; ++nt) {
            int NT = wid * 6 + nt;
            const float* wp = w_qkv + (size_t)(NT * 16 + lrow) * CDIM + ks * 32 + lgrp * 8;
            float x[8];
            *(float4*)(x)     = *(const float4*)wp;
            *(float4*)(x + 4) = *(const float4*)(wp + 4);
            short8v bH, bL;
            split8(x, bH, bL);
            #pragma unroll
            for (int mt = 0; mt < 3; ++mt) {
                acc[mt][nt] = __builtin_amdgcn_mfma_f32_16x16x32_bf16(aH[mt], bH, acc[mt][nt], 0, 0, 0);
                acc[mt][nt] = __builtin_amdgcn_mfma_f32_16x16x32_bf16(aL[mt], bH, acc[mt][nt], 0, 0, 0);
                acc[mt][nt] = __builtin_amdgcn_mfma_f32_16x16x32_bf16(aH[mt], bL, acc[mt][nt], 0, 0, 0);
            }
        }
    }
    __syncthreads();

    #pragma unroll
    for (int nt = 0; nt < 6; ++nt) {
        int NT   = wid * 6 + nt;
        int type = NT >> 3;
        int hh   = NT & 7;
        int d    = lrow;
        float bq = b_qkv[NT * 16 + lrow];
        float scale = (type == 0) ? QSCALE : 1.0f;
        #pragma unroll
        for (int mt = 0; mt < 3; ++mt)
            #pragma unroll
            for (int r = 0; r < 4; ++r) {
                int m = mt * 16 + lgrp * 4 + r;
                unsigned short b = bf16r((acc[mt][nt][r] + bq) * scale);
                int addr;
                if (type < 2) {
                    addr = type * KOFF + hh * 1536 + m * 32
                         + (((d >> 2) ^ (m >> 2)) & 3) * 8 + (d & 3) * 2;
                } else {
                    int mb = m >> 2;
                    addr = VOFF + hh * 1536 + d * 96
                         + (((mb & ~3) | ((mb ^ (d >> 2)) & 3))) * 8 + (m & 3) * 2;
                }
                *(unsigned short*)(uni + addr) = b;
            }
    }
    __syncthreads();

    f32x4 oall[2][3];
    #pragma unroll
    for (int ht = 0; ht < 2; ++ht) {
        const int h = wid * 2 + ht;
        short8v kf[3], qf[3];
        #pragma unroll
        for (int t = 0; t < 3; ++t) {
            int row = t * 16 + lrow;
            int ra  = row * 32 + (((lgrp ^ (row >> 2)) & 3)) * 8;
            short4v kq = *(const short4v*)(uni + KOFF + h * 1536 + ra);
            short4v qq = *(const short4v*)(uni +        h * 1536 + ra);
            short8v a, b;
            a[0]=kq[0]; a[1]=kq[1]; a[2]=kq[2]; a[3]=kq[3]; a[4]=0; a[5]=0; a[6]=0; a[7]=0;
            b[0]=qq[0]; b[1]=qq[1]; b[2]=qq[2]; b[3]=qq[3]; b[4]=0; b[5]=0; b[6]=0; b[7]=0;
            kf[t] = a; qf[t] = b;
        }
        f32x4 s[3][3];
        #pragma unroll
        for (int qt = 0; qt < 3; ++qt)
            #pragma unroll
            for (int mt = 0; mt < 3; ++mt)
                s[qt][mt] = __builtin_amdgcn_mfma_f32_16x16x32_bf16(kf[mt], qf[qt], (f32x4)0.0f, 0, 0, 0);

        #pragma unroll
        for (int qt = 0; qt < 3; ++qt) {
            int q  = qt * 16 + lrow;
            int gx = gcl[q][0], gy = gcl[q][1], gz = gcl[q][2];
            #pragma unroll
            for (int mt = 0; mt < 3; ++mt)
                #pragma unroll
                for (int r = 0; r < 4; ++r) {
                    int m  = mt * 16 + lgrp * 4 + r;
                    int rx = gx - gcl[m][0];
                    int ry = gy - gcl[m][1];
                    int rz = gz - gcl[m][2];
                    rx = rx < -POS_BND ? -POS_BND : (rx > POS_BND ? POS_BND : rx);
                    ry = ry < -POS_BND ? -POS_BND : (ry > POS_BND ? POS_BND : ry);
                    rz = rz < -POS_BND ? -POS_BND : (rz > POS_BND ? POS_BND : rz);
                    s[qt][mt][r] += rpe_l[(rx + POS_BND) * HH + h]
                                  + rpe_l[(ry + POS_BND + RPE_NUM) * HH + h]
                                  + rpe_l[(rz + POS_BND + 2 * RPE_NUM) * HH + h];
                }
        }

        #pragma unroll
        for (int qt = 0; qt < 3; ++qt) {
            float mx = -1e30f;
            #pragma unroll
            for (int mt = 0; mt < 3; ++mt)
                #pragma unroll
                for (int r = 0; r < 4; ++r) mx = fmaxf(mx, s[qt][mt][r]);
            mx = fmaxf(mx, __shfl_xor(mx, 16));
            mx = fmaxf(mx, __shfl_xor(mx, 32));
            float sum = 0.f;
            #pragma unroll
            for (int mt = 0; mt < 3; ++mt)
                #pragma unroll
                for (int r = 0; r < 4; ++r) {
                    float e = __expf(s[qt][mt][r] - mx);
                    s[qt][mt][r] = e;
                    sum += e;
                }
            sum += __shfl_xor(sum, 16);
            sum += __shfl_xor(sum, 32);
            float inv = 1.0f / sum;
            #pragma unroll
            for (int mt = 0; mt < 3; ++mt)
                #pragma unroll
                for (int r = 0; r < 4; ++r) s[qt][mt][r] *= inv;
        }

        short8v vb0, vb1;
        {
            int base = VOFF + h * 1536 + lrow * 96 + (((lgrp ^ (lrow >> 2)) & 3)) * 8;
            short4v x0 = *(const short4v*)(uni + base);
            short4v x1 = *(const short4v*)(uni + base + 32);
            short4v x2 = *(const short4v*)(uni + base + 64);
            vb0[0]=x0[0]; vb0[1]=x0[1]; vb0[2]=x0[2]; vb0[3]=x0[3];
            vb0[4]=x1[0]; vb0[5]=x1[1]; vb0[6]=x1[2]; vb0[7]=x1[3];
            vb1[0]=x2[0]; vb1[1]=x2[1]; vb1[2]=x2[2]; vb1[3]=x2[3];
            vb1[4]=0; vb1[5]=0; vb1[6]=0; vb1[7]=0;
        }
        #pragma unroll
        for (int qt = 0; qt < 3; ++qt) {
            short8v pa0, pa1;
            #pragma unroll
            for (int j = 0; j < 4; ++j) {
                pa0[j]     = (short)bf16r(s[qt][0][j]);
                pa0[4 + j] = (short)bf16r(s[qt][1][j]);
                pa1[j]     = (short)bf16r(s[qt][2][j]);
                pa1[4 + j] = 0;
            }
            f32x4 o = __builtin_amdgcn_mfma_f32_16x16x32_bf16(pa0, vb0, (f32x4)0.0f, 0, 0, 0);
            o = __builtin_amdgcn_mfma_f32_16x16x32_bf16(pa1, vb1, o, 0, 0, 0);
            oall[ht][qt] = o;
        }
    }
    __syncthreads();

    #pragma unroll
    for (int ht = 0; ht < 2; ++ht) {
        int c = (wid * 2 + ht) * 16 + lrow;
        #pragma unroll
        for (int qt = 0; qt < 3; ++qt)
            #pragma unroll
            for (int r = 0; r < 4; ++r) {
                int q = qt * 16 + lgrp * 4 + r;
                float x = oall[ht][qt][r];
                unsigned u = __float_as_uint(x);
                unsigned short h16 = (unsigned short)(u >> 16);
                float lres = x - __uint_as_float(u & 0xffff0000u);
                unsigned short l16 = (unsigned short)(__float_as_uint(lres) >> 16);
                int addr = (q * 256 + c * 2) ^ ((q & 7) << 4);
                *(unsigned short*)(uni + addr)        = h16;
                *(unsigned short*)(uni + KOFF + addr) = l16;
            }
    }
    __syncthreads();

    f32x4 pacc[3][2];
    #pragma unroll
    for (int i = 0; i < 3; ++i)
        #pragma unroll
        for (int j = 0; j < 2; ++j) pacc[i][j] = (f32x4)0.0f;

    #pragma unroll
    for (int ks = 0; ks < 4; ++ks) {
        short8v aH[3], aL[3];
        #pragma unroll
        for (int mt = 0; mt < 3; ++mt) {
            int row  = mt * 16 + lrow;
            int boff = (row * 256 + ks * 64 + lgrp * 16) ^ ((row & 7) << 4);
            aH[mt] = *(const short8v*)(uni + boff);
            aL[mt] = *(const short8v*)(uni + KOFF + boff);
        }
        #pragma unroll
        for (int nt = 0; nt < 2; ++nt) {
            int NT = wid * 2 + nt;
            const float* wp = w_proj + (size_t)(NT * 16 + lrow) * CDIM + ks * 32 + lgrp * 8;
            float x[8];
            *(float4*)(x)     = *(const float4*)wp;
            *(float4*)(x + 4) = *(const float4*)(wp + 4);
            short8v bH, bL;
            split8(x, bH, bL);
            #pragma unroll
            for (int mt = 0; mt < 3; ++mt) {
                pacc[mt][nt] = __builtin_amdgcn_mfma_f32_16x16x32_bf16(aH[mt], bH, pacc[mt][nt], 0, 0, 0);
                pacc[mt][nt] = __builtin_amdgcn_mfma_f32_16x16x32_bf16(aL[mt], bH, pacc[mt][nt], 0, 0, 0);
                pacc[mt][nt] = __builtin_amdgcn_mfma_f32_16x16x32_bf16(aH[mt], bL, pacc[mt][nt], 0, 0, 0);
            }
        }
    }
    __syncthreads();

    float* ot = (float*)uni;
    #pragma unroll
    for (int nt = 0; nt < 2; ++nt) {
        int NT = wid * 2 + nt;
        int c  = NT * 16 + lrow;
        float bp = b_proj[c];
        #pragma unroll
        for (int mt = 0; mt < 3; ++mt)
            #pragma unroll
            for (int r = 0; r < 4; ++r) {
                int row = mt * 16 + lgrp * 4 + r;
                ot[row * OTS + c] = pacc[mt][nt][r] + bp;
            }
    }
    __syncthreads();

    for (int e = tid; e < KPATCH * 32; e += 256) {
        int r  = e >> 5;
        int c4 = e & 31;
        f4v v = *(const f4v*)&ot[r * OTS + c4 * 4];
        __builtin_nontemporal_store(v, (f4v*)(out + (size_t)ord[r] * CDIM + c4 * 4));
    }
}

extern "C" void kernel_launch(void* const* d_in, const int* in_sizes, int n_in,
                              void* d_out, int out_size, void* d_ws, size_t ws_size,
                              hipStream_t stream) {
    const float* feat   = (const float*)d_in[0];
    const float* w_qkv  = (const float*)d_in[1];
    const float* b_qkv  = (const float*)d_in[2];
    const float* w_proj = (const float*)d_in[3];
    const float* b_proj = (const float*)d_in[4];
    const float* rpe    = (const float*)d_in[5];
    const int*   order  = (const int*)d_in[6];
    const int*   inv    = (const int*)d_in[7];
    const int*   gc     = (const int*)d_in[8];
    float* out = (float*)d_out;

    const size_t need1 = (size_t)NPTS * QKVB;                 // 226,492,416 B
    const size_t need2 = need1 + (size_t)NPTS * CDIM * 4;     // + 151,001,088 B

    if (ws_size >= need1) {
        unsigned short* qkv_ws = (unsigned short*)d_ws;
        k1_qkv<<<NPTS / K1ROWS, 256, 0, stream>>>(feat, w_qkv, b_qkv, qkv_ws);
        if (ws_size >= need2) {
            float* ws2 = (float*)((char*)d_ws + need1);
            k2_attn<<<NP, 256, 0, stream>>>(qkv_ws, w_proj, b_proj, rpe, order, gc, ws2, 1);
            k3_perm<<<NPTS / 64, 256, 0, stream>>>(ws2, inv, out);
        } else {
            k2_attn<<<NP, 256, 0, stream>>>(qkv_ws, w_proj, b_proj, rpe, order, gc, out, 0);
        }
    } else {
        fused_patch_attn<<<NP, 256, 0, stream>>>(feat, w_qkv, b_qkv, w_proj, b_proj,
                                                 rpe, order, gc, out);
    }
}

// Round 7
// 313.054 us; speedup vs baseline: 2.3972x; 2.3972x over previous
//
#include <hip/hip_runtime.h>

#define NPTS 294912
#define CDIM 128
#define HH 8
#define KPATCH 48
#define DD 16
#define NP (NPTS / KPATCH)      // 6144 patches
#define POS_BND 11
#define RPE_NUM 23
#define RPE_ROWS (3 * RPE_NUM)  // 69
#define QSCALE 0.25f

typedef __attribute__((ext_vector_type(8))) short short8v;  // 8 bf16
typedef __attribute__((ext_vector_type(4))) short short4v;  // 4 bf16
typedef __attribute__((ext_vector_type(4))) float f32x4;
typedef __attribute__((ext_vector_type(4))) float f4v;

// LDS union (36864 B):
//  Phase A (QKV GEMM):  featH [48][256B] @0 (12288) | featL @12288   (XOR (row&7)<<4)
//  Phase B (attention): Q bf16 @0 [8][48][32B], K @12288, Vt @24576 [8][16][96B]
//  Phase C (proj GEMM): aoH @0 | aoL @12288   (same layout/swizzle as feat)
#define UNI_BYTES 36864
#define KOFF 12288
#define VOFF 24576

__device__ __forceinline__ unsigned short bf16r(float x) {   // RNE bf16
    unsigned u = __float_as_uint(x);
    return (unsigned short)((u + 0x7fffu + ((u >> 16) & 1u)) >> 16);
}

__device__ __forceinline__ void split8(const float* x, short8v& hi, short8v& lo) {
    #pragma unroll
    for (int i = 0; i < 8; ++i) {
        unsigned u = __float_as_uint(x[i]);
        hi[i] = (short)(u >> 16);                           // truncated bf16
        float l = x[i] - __uint_as_float(u & 0xffff0000u);  // exact residual
        lo[i] = (short)(__float_as_uint(l) >> 16);
    }
}

// launch_bounds(256,2): cap 256 regs -> NO scratch spills. r4's (256,4) forced
// VGPR_Count=64 and spilled ~1 GB/dispatch of scratch traffic (the r4-r6 WRITE_SIZE
// mystery). Occupancy beyond 2 blocks/CU comes free if natural reg use <= 128.
__global__ __launch_bounds__(256, 2) void fused_patch_attn(
    const float* __restrict__ feat,
    const float* __restrict__ w_qkv,
    const float* __restrict__ b_qkv,
    const float* __restrict__ w_proj,
    const float* __restrict__ b_proj,
    const float* __restrict__ rpe,
    const int* __restrict__ order,
    const int* __restrict__ grid_coord,
    float* __restrict__ out)
{
    __shared__ int ord[KPATCH];
    __shared__ int gcl[KPATCH][3];
    __shared__ float rpe_l[RPE_ROWS * HH];
    __shared__ __align__(16) char uni[UNI_BYTES];

    const int p    = blockIdx.x;
    const int tid  = threadIdx.x;
    const int wid  = tid >> 6;
    const int lane = tid & 63;
    const int lrow = lane & 15;     // fragment row/col lane index
    const int lgrp = lane >> 4;     // k-group 0..3

    if (tid < KPATCH) {
        int o = order[p * KPATCH + tid];
        ord[tid] = o;
        gcl[tid][0] = grid_coord[o * 3 + 0];
        gcl[tid][1] = grid_coord[o * 3 + 1];
        gcl[tid][2] = grid_coord[o * 3 + 2];
    }
    for (int e = tid; e < RPE_ROWS * HH; e += 256) rpe_l[e] = rpe[e];
    __syncthreads();

    // ---- gather feat rows (48 x 128, non-temporal) -> bf16 hi/lo tiles ----
    for (int e = tid; e < KPATCH * 16; e += 256) {
        int r  = e >> 4;
        int c8 = e & 15;
        const float* src = feat + (size_t)ord[r] * CDIM + c8 * 8;
        float x[8];
        *(f4v*)(x)     = __builtin_nontemporal_load((const f4v*)src);
        *(f4v*)(x + 4) = __builtin_nontemporal_load((const f4v*)(src + 4));
        short8v hi, lo;
        split8(x, hi, lo);
        int addr = (r * 256 + c8 * 16) ^ ((r & 7) << 4);
        *(short8v*)(uni + addr)        = hi;
        *(short8v*)(uni + KOFF + addr) = lo;
    }
    __syncthreads();

    // ---- QKV GEMM via split-bf16 MFMA: M=48 (3 mt), N=384 (6 nt/wave), K=128 ----
    f32x4 acc[3][6];
    #pragma unroll
    for (int i = 0; i < 3; ++i)
        #pragma unroll
        for (int j = 0; j < 6; ++j) acc[i][j] = (f32x4)0.0f;

    #pragma unroll
    for (int ks = 0; ks < 4; ++ks) {
        short8v aH[3], aL[3];
        #pragma unroll
        for (int mt = 0; mt < 3; ++mt) {
            int row  = mt * 16 + lrow;
            int boff = (row * 256 + ks * 64 + lgrp * 16) ^ ((row & 7) << 4);
            aH[mt] = *(const short8v*)(uni + boff);
            aL[mt] = *(const short8v*)(uni + KOFF + boff);
        }
        #pragma unroll
        for (int nt = 0; nt < 6; ++nt) {
            int NT = wid * 6 + nt;
            const float* wp = w_qkv + (size_t)(NT * 16 + lrow) * CDIM + ks * 32 + lgrp * 8;
            float x[8];
            *(float4*)(x)     = *(const float4*)wp;
            *(float4*)(x + 4) = *(const float4*)(wp + 4);
            short8v bH, bL;
            split8(x, bH, bL);
            #pragma unroll
            for (int mt = 0; mt < 3; ++mt) {
                acc[mt][nt] = __builtin_amdgcn_mfma_f32_16x16x32_bf16(aH[mt], bH, acc[mt][nt], 0, 0, 0);
                acc[mt][nt] = __builtin_amdgcn_mfma_f32_16x16x32_bf16(aL[mt], bH, acc[mt][nt], 0, 0, 0);
                acc[mt][nt] = __builtin_amdgcn_mfma_f32_16x16x32_bf16(aH[mt], bL, acc[mt][nt], 0, 0, 0);
            }
        }
    }
    __syncthreads();   // feat tile reads done; region becomes Q/K/Vt bf16

    // ---- write qkv accumulators (+bias, q*scale) as bf16 into Q/K/Vt ----
    // Q/K: [h][m][32B row], d-group unit 8B swizzled by XOR with (m>>2)&3
    // Vt:  [h][d][96B row], m-group unit 8B swizzled by XOR with (d>>2)&3
    #pragma unroll
    for (int nt = 0; nt < 6; ++nt) {
        int NT   = wid * 6 + nt;
        int type = NT >> 3;          // 0=q 1=k 2=v (uniform per wave-tile)
        int hh   = NT & 7;
        int d    = lrow;
        float bq = b_qkv[NT * 16 + lrow];
        float scale = (type == 0) ? QSCALE : 1.0f;
        #pragma unroll
        for (int mt = 0; mt < 3; ++mt)
            #pragma unroll
            for (int r = 0; r < 4; ++r) {
                int m = mt * 16 + lgrp * 4 + r;
                unsigned short b = bf16r((acc[mt][nt][r] + bq) * scale);
                int addr;
                if (type < 2) {
                    addr = type * KOFF + hh * 1536 + m * 32
                         + (((d >> 2) ^ (m >> 2)) & 3) * 8 + (d & 3) * 2;
                } else {
                    int mb = m >> 2;
                    addr = VOFF + hh * 1536 + d * 96
                         + (((mb & ~3) | ((mb ^ (d >> 2)) & 3))) * 8 + (m & 3) * 2;
                }
                *(unsigned short*)(uni + addr) = b;
            }
    }
    __syncthreads();

    // ---- MFMA attention: 2 heads per wave ----
    f32x4 oall[2][3];
    #pragma unroll
    for (int ht = 0; ht < 2; ++ht) {
        const int h = wid * 2 + ht;
        // K A-frags (rows m) and Q B-frags (cols q): k-slots 0-3 = d, 4-7 = zero pad
        short8v kf[3], qf[3];
        #pragma unroll
        for (int t = 0; t < 3; ++t) {
            int row = t * 16 + lrow;
            int ra  = row * 32 + (((lgrp ^ (row >> 2)) & 3)) * 8;
            short4v kq = *(const short4v*)(uni + KOFF + h * 1536 + ra);
            short4v qq = *(const short4v*)(uni +        h * 1536 + ra);
            short8v a, b;
            a[0]=kq[0]; a[1]=kq[1]; a[2]=kq[2]; a[3]=kq[3]; a[4]=0; a[5]=0; a[6]=0; a[7]=0;
            b[0]=qq[0]; b[1]=qq[1]; b[2]=qq[2]; b[3]=qq[3]; b[4]=0; b[5]=0; b[6]=0; b[7]=0;
            kf[t] = a; qf[t] = b;
        }
        // S[m][q] tiles: C row = m local (lgrp*4+r), col = q local (lrow)
        f32x4 s[3][3];
        #pragma unroll
        for (int qt = 0; qt < 3; ++qt)
            #pragma unroll
            for (int mt = 0; mt < 3; ++mt)
                s[qt][mt] = __builtin_amdgcn_mfma_f32_16x16x32_bf16(kf[mt], qf[qt], (f32x4)0.0f, 0, 0, 0);

        // relative-position bias
        #pragma unroll
        for (int qt = 0; qt < 3; ++qt) {
            int q  = qt * 16 + lrow;
            int gx = gcl[q][0], gy = gcl[q][1], gz = gcl[q][2];
            #pragma unroll
            for (int mt = 0; mt < 3; ++mt)
                #pragma unroll
                for (int r = 0; r < 4; ++r) {
                    int m  = mt * 16 + lgrp * 4 + r;
                    int rx = gx - gcl[m][0];
                    int ry = gy - gcl[m][1];
                    int rz = gz - gcl[m][2];
                    rx = rx < -POS_BND ? -POS_BND : (rx > POS_BND ? POS_BND : rx);
                    ry = ry < -POS_BND ? -POS_BND : (ry > POS_BND ? POS_BND : ry);
                    rz = rz < -POS_BND ? -POS_BND : (rz > POS_BND ? POS_BND : rz);
                    s[qt][mt][r] += rpe_l[(rx + POS_BND) * HH + h]
                                  + rpe_l[(ry + POS_BND + RPE_NUM) * HH + h]
                                  + rpe_l[(rz + POS_BND + 2 * RPE_NUM) * HH + h];
                }
        }

        // softmax over m (12 local + cross-lane over row-groups: lanes l^16, l^32)
        #pragma unroll
        for (int qt = 0; qt < 3; ++qt) {
            float mx = -1e30f;
            #pragma unroll
            for (int mt = 0; mt < 3; ++mt)
                #pragma unroll
                for (int r = 0; r < 4; ++r) mx = fmaxf(mx, s[qt][mt][r]);
            mx = fmaxf(mx, __shfl_xor(mx, 16));
            mx = fmaxf(mx, __shfl_xor(mx, 32));
            float sum = 0.f;
            #pragma unroll
            for (int mt = 0; mt < 3; ++mt)
                #pragma unroll
                for (int r = 0; r < 4; ++r) {
                    float e = __expf(s[qt][mt][r] - mx);
                    s[qt][mt][r] = e;
                    sum += e;
                }
            sum += __shfl_xor(sum, 16);
            sum += __shfl_xor(sum, 32);
            float inv = 1.0f / sum;
            #pragma unroll
            for (int mt = 0; mt < 3; ++mt)
                #pragma unroll
                for (int r = 0; r < 4; ++r) s[qt][mt][r] *= inv;
        }

        // V B-frags: custom k-slot map {j0-3: m=ms*32+lgrp*4+j, j4-7: +16} matching P regs
        short8v vb0, vb1;
        {
            int base = VOFF + h * 1536 + lrow * 96 + (((lgrp ^ (lrow >> 2)) & 3)) * 8;
            short4v x0 = *(const short4v*)(uni + base);        // m 0..15 group
            short4v x1 = *(const short4v*)(uni + base + 32);   // m 16..31 group
            short4v x2 = *(const short4v*)(uni + base + 64);   // m 32..47 group
            vb0[0]=x0[0]; vb0[1]=x0[1]; vb0[2]=x0[2]; vb0[3]=x0[3];
            vb0[4]=x1[0]; vb0[5]=x1[1]; vb0[6]=x1[2]; vb0[7]=x1[3];
            vb1[0]=x2[0]; vb1[1]=x2[1]; vb1[2]=x2[2]; vb1[3]=x2[3];
            vb1[4]=0; vb1[5]=0; vb1[6]=0; vb1[7]=0;
        }
        // PV: out[q][d] per qt; P regs are already A-fragments under the same k-slot map
        #pragma unroll
        for (int qt = 0; qt < 3; ++qt) {
            short8v pa0, pa1;
            #pragma unroll
            for (int j = 0; j < 4; ++j) {
                pa0[j]     = (short)bf16r(s[qt][0][j]);
                pa0[4 + j] = (short)bf16r(s[qt][1][j]);
                pa1[j]     = (short)bf16r(s[qt][2][j]);
                pa1[4 + j] = 0;
            }
            f32x4 o = __builtin_amdgcn_mfma_f32_16x16x32_bf16(pa0, vb0, (f32x4)0.0f, 0, 0, 0);
            o = __builtin_amdgcn_mfma_f32_16x16x32_bf16(pa1, vb1, o, 0, 0, 0);
            oall[ht][qt] = o;
        }
    }
    __syncthreads();   // all qkv reads done; region becomes aoH/aoL

    // ---- write attention output hi/lo bf16 tile (same layout/swizzle as feat) ----
    #pragma unroll
    for (int ht = 0; ht < 2; ++ht) {
        int c = (wid * 2 + ht) * 16 + lrow;     // output column = h*16 + d
        #pragma unroll
        for (int qt = 0; qt < 3; ++qt)
            #pragma unroll
            for (int r = 0; r < 4; ++r) {
                int q = qt * 16 + lgrp * 4 + r; // output row
                float x = oall[ht][qt][r];
                unsigned u = __float_as_uint(x);
                unsigned short h16 = (unsigned short)(u >> 16);
                float lres = x - __uint_as_float(u & 0xffff0000u);
                unsigned short l16 = (unsigned short)(__float_as_uint(lres) >> 16);
                int addr = (q * 256 + c * 2) ^ ((q & 7) << 4);
                *(unsigned short*)(uni + addr)        = h16;
                *(unsigned short*)(uni + KOFF + addr) = l16;
            }
    }
    __syncthreads();

    // ---- proj GEMM via split-bf16 MFMA: M=48, N=128 (2 nt/wave), K=128 ----
    f32x4 pacc[3][2];
    #pragma unroll
    for (int i = 0; i < 3; ++i)
        #pragma unroll
        for (int j = 0; j < 2; ++j) pacc[i][j] = (f32x4)0.0f;

    #pragma unroll
    for (int ks = 0; ks < 4; ++ks) {
        short8v aH[3], aL[3];
        #pragma unroll
        for (int mt = 0; mt < 3; ++mt) {
            int row  = mt * 16 + lrow;
            int boff = (row * 256 + ks * 64 + lgrp * 16) ^ ((row & 7) << 4);
            aH[mt] = *(const short8v*)(uni + boff);
            aL[mt] = *(const short8v*)(uni + KOFF + boff);
        }
        #pragma unroll
        for (int nt = 0; nt < 2; ++nt) {
            int NT = wid * 2 + nt;
            const float* wp = w_proj + (size_t)(NT * 16 + lrow) * CDIM + ks * 32 + lgrp * 8;
            float x[8];
            *(float4*)(x)     = *(const float4*)wp;
            *(float4*)(x + 4) = *(const float4*)(wp + 4);
            short8v bH, bL;
            split8(x, bH, bL);
            #pragma unroll
            for (int mt = 0; mt < 3; ++mt) {
                pacc[mt][nt] = __builtin_amdgcn_mfma_f32_16x16x32_bf16(aH[mt], bH, pacc[mt][nt], 0, 0, 0);
                pacc[mt][nt] = __builtin_amdgcn_mfma_f32_16x16x32_bf16(aL[mt], bH, pacc[mt][nt], 0, 0, 0);
                pacc[mt][nt] = __builtin_amdgcn_mfma_f32_16x16x32_bf16(aH[mt], bL, pacc[mt][nt], 0, 0, 0);
            }
        }
    }

    // ---- scatter rows to out (+bias) ----
    #pragma unroll
    for (int nt = 0; nt < 2; ++nt) {
        int NT = wid * 2 + nt;
        int c  = NT * 16 + lrow;
        float bp = b_proj[c];
        #pragma unroll
        for (int mt = 0; mt < 3; ++mt)
            #pragma unroll
            for (int r = 0; r < 4; ++r) {
                int row = mt * 16 + lgrp * 4 + r;
                out[(size_t)ord[row] * CDIM + c] = pacc[mt][nt][r] + bp;
            }
    }
}

extern "C" void kernel_launch(void* const* d_in, const int* in_sizes, int n_in,
                              void* d_out, int out_size, void* d_ws, size_t ws_size,
                              hipStream_t stream) {
    const float* feat   = (const float*)d_in[0];
    const float* w_qkv  = (const float*)d_in[1];
    const float* b_qkv  = (const float*)d_in[2];
    const float* w_proj = (const float*)d_in[3];
    const float* b_proj = (const float*)d_in[4];
    const float* rpe    = (const float*)d_in[5];
    const int*   order  = (const int*)d_in[6];
    const int*   gc     = (const int*)d_in[8];
    float* out = (float*)d_out;

    fused_patch_attn<<<NP, 256, 0, stream>>>(feat, w_qkv, b_qkv, w_proj, b_proj,
                                             rpe, order, gc, out);
}

// Round 8
// 217.117 us; speedup vs baseline: 3.4565x; 1.4419x over previous
//
#include <hip/hip_runtime.h>

#define NPTS 294912
#define CDIM 128
#define HH 8
#define KPATCH 48
#define DD 16
#define NP (NPTS / KPATCH)      // 6144 patches
#define POS_BND 11
#define RPE_NUM 23
#define RPE_ROWS (3 * RPE_NUM)  // 69
#define QSCALE 0.25f

typedef __attribute__((ext_vector_type(8))) short short8v;  // 8 bf16
typedef __attribute__((ext_vector_type(4))) short short4v;  // 4 bf16
typedef __attribute__((ext_vector_type(4))) float f32x4;
typedef __attribute__((ext_vector_type(4))) float f4v;

// Pre-split weights: w_qkv (49152) then w_proj (16384) = 65536 elems.
// hi = RNE bf16, lo = RNE(x - hi). Rebuilt every call (deterministic).
__device__ __align__(16) unsigned short g_whi[65536];
__device__ __align__(16) unsigned short g_wlo[65536];

// LDS union (36864 B):
//  Phase A (QKV GEMM):  featH [48][256B] @0 (12288) | featL @12288   (XOR (row&7)<<4)
//  Phase B (attention): Q bf16 @0 [8][48][32B], K @12288, Vt @24576 [8][16][96B]
//  Phase C (proj GEMM): aoH @0 | aoL @12288   (same layout/swizzle as feat)
#define UNI_BYTES 36864
#define KOFF 12288
#define VOFF 24576

__device__ __forceinline__ unsigned short bf16r(float x) {   // RNE bf16
    unsigned u = __float_as_uint(x);
    return (unsigned short)((u + 0x7fffu + ((u >> 16) & 1u)) >> 16);
}

__device__ __forceinline__ void split8(const float* x, short8v& hi, short8v& lo) {
    #pragma unroll
    for (int i = 0; i < 8; ++i) {
        unsigned u = __float_as_uint(x[i]);
        hi[i] = (short)(u >> 16);                           // truncated bf16
        float l = x[i] - __uint_as_float(u & 0xffff0000u);  // exact residual
        lo[i] = (short)(__float_as_uint(l) >> 16);
    }
}

__global__ __launch_bounds__(256) void prep_w(const float* __restrict__ w_qkv,
                                              const float* __restrict__ w_proj) {
    int gid = blockIdx.x * 256 + threadIdx.x;   // 16384 threads x 4 elems
    float x[4];
    if (gid < 12288) *(f4v*)x = ((const f4v*)w_qkv)[gid];
    else             *(f4v*)x = ((const f4v*)w_proj)[gid - 12288];
    short4v hi, lo;
    #pragma unroll
    for (int i = 0; i < 4; ++i) {
        unsigned short h = bf16r(x[i]);
        hi[i] = (short)h;
        float hf = __uint_as_float((unsigned)h << 16);
        lo[i] = (short)bf16r(x[i] - hf);
    }
    *(short4v*)&g_whi[gid * 4] = hi;
    *(short4v*)&g_wlo[gid * 4] = lo;
}

// 512 threads = 8 waves; (512,4) => 4 waves/EU min => 2 blocks/CU (16 waves), reg cap 128.
// Per-wave tiles halved vs r7 (QKV 3 nt, attn 1 head, proj 1 nt) to genuinely fit 128.
__global__ __launch_bounds__(512, 4) void fused_patch_attn(
    const float* __restrict__ feat,
    const float* __restrict__ b_qkv,
    const float* __restrict__ b_proj,
    const float* __restrict__ rpe,
    const int* __restrict__ order,
    const int* __restrict__ grid_coord,
    float* __restrict__ out)
{
    __shared__ int ord[KPATCH];
    __shared__ int gcl[KPATCH][3];
    __shared__ float rpe_t[HH * RPE_ROWS];   // transposed [h][69]: bank-spread lookups
    __shared__ __align__(16) char uni[UNI_BYTES];

    const int p    = blockIdx.x;
    const int tid  = threadIdx.x;
    const int wid  = tid >> 6;      // 0..7
    const int lane = tid & 63;
    const int lrow = lane & 15;     // fragment row/col lane index
    const int lgrp = lane >> 4;     // k-group 0..3

    if (tid < KPATCH) {
        int o = order[p * KPATCH + tid];
        ord[tid] = o;
        gcl[tid][0] = grid_coord[o * 3 + 0];
        gcl[tid][1] = grid_coord[o * 3 + 1];
        gcl[tid][2] = grid_coord[o * 3 + 2];
    }
    for (int e = tid; e < HH * RPE_ROWS; e += 512) {
        int h = e / RPE_ROWS;
        int i = e - h * RPE_ROWS;
        rpe_t[e] = rpe[i * HH + h];
    }
    __syncthreads();

    // ---- gather feat rows (48 x 128, non-temporal) -> bf16 hi/lo tiles ----
    for (int e = tid; e < KPATCH * 16; e += 512) {
        int r  = e >> 4;
        int c8 = e & 15;
        const float* src = feat + (size_t)ord[r] * CDIM + c8 * 8;
        float x[8];
        *(f4v*)(x)     = __builtin_nontemporal_load((const f4v*)src);
        *(f4v*)(x + 4) = __builtin_nontemporal_load((const f4v*)(src + 4));
        short8v hi, lo;
        split8(x, hi, lo);
        int addr = (r * 256 + c8 * 16) ^ ((r & 7) << 4);
        *(short8v*)(uni + addr)        = hi;
        *(short8v*)(uni + KOFF + addr) = lo;
    }
    __syncthreads();

    // ---- QKV GEMM: M=48 (3 mt), N=384 (3 nt/wave x 8 waves), K=128 ----
    // split-A x single-B (r6-proven accuracy): 2 MFMA per (mt,nt,ks)
    f32x4 acc[3][3];
    #pragma unroll
    for (int i = 0; i < 3; ++i)
        #pragma unroll
        for (int j = 0; j < 3; ++j) acc[i][j] = (f32x4)0.0f;

    #pragma unroll
    for (int ks = 0; ks < 4; ++ks) {
        short8v aH[3], aL[3];
        #pragma unroll
        for (int mt = 0; mt < 3; ++mt) {
            int row  = mt * 16 + lrow;
            int boff = (row * 256 + ks * 64 + lgrp * 16) ^ ((row & 7) << 4);
            aH[mt] = *(const short8v*)(uni + boff);
            aL[mt] = *(const short8v*)(uni + KOFF + boff);
        }
        #pragma unroll
        for (int nt = 0; nt < 3; ++nt) {
            int NT = wid * 3 + nt;
            short8v bH = *(const short8v*)&g_whi[(NT * 16 + lrow) * CDIM + ks * 32 + lgrp * 8];
            #pragma unroll
            for (int mt = 0; mt < 3; ++mt) {
                acc[mt][nt] = __builtin_amdgcn_mfma_f32_16x16x32_bf16(aH[mt], bH, acc[mt][nt], 0, 0, 0);
                acc[mt][nt] = __builtin_amdgcn_mfma_f32_16x16x32_bf16(aL[mt], bH, acc[mt][nt], 0, 0, 0);
            }
        }
    }
    __syncthreads();   // feat tile reads done; region becomes Q/K/Vt bf16

    // ---- write qkv accumulators (+bias, q*scale) as bf16 into Q/K/Vt ----
    #pragma unroll
    for (int nt = 0; nt < 3; ++nt) {
        int NT   = wid * 3 + nt;
        int type = NT >> 3;          // 0=q 1=k 2=v (uniform per wave-tile)
        int hh   = NT & 7;
        int d    = lrow;
        float bq = b_qkv[NT * 16 + lrow];
        float scale = (type == 0) ? QSCALE : 1.0f;
        #pragma unroll
        for (int mt = 0; mt < 3; ++mt)
            #pragma unroll
            for (int r = 0; r < 4; ++r) {
                int m = mt * 16 + lgrp * 4 + r;
                unsigned short b = bf16r((acc[mt][nt][r] + bq) * scale);
                int addr;
                if (type < 2) {
                    addr = type * KOFF + hh * 1536 + m * 32
                         + (((d >> 2) ^ (m >> 2)) & 3) * 8 + (d & 3) * 2;
                } else {
                    int mb = m >> 2;
                    addr = VOFF + hh * 1536 + d * 96
                         + (((mb & ~3) | ((mb ^ (d >> 2)) & 3))) * 8 + (m & 3) * 2;
                }
                *(unsigned short*)(uni + addr) = b;
            }
    }
    __syncthreads();

    // ---- MFMA attention: ONE head per wave (h = wid) ----
    const int h = wid;
    const float* rbase = &rpe_t[h * RPE_ROWS];
    f32x4 oall[3];
    {
        // K A-frags (rows m) and Q B-frags (cols q): k-slots 0-3 = d, 4-7 = zero pad
        short8v kf[3], qf[3];
        #pragma unroll
        for (int t = 0; t < 3; ++t) {
            int row = t * 16 + lrow;
            int ra  = row * 32 + (((lgrp ^ (row >> 2)) & 3)) * 8;
            short4v kq = *(const short4v*)(uni + KOFF + h * 1536 + ra);
            short4v qq = *(const short4v*)(uni +        h * 1536 + ra);
            short8v a, b;
            a[0]=kq[0]; a[1]=kq[1]; a[2]=kq[2]; a[3]=kq[3]; a[4]=0; a[5]=0; a[6]=0; a[7]=0;
            b[0]=qq[0]; b[1]=qq[1]; b[2]=qq[2]; b[3]=qq[3]; b[4]=0; b[5]=0; b[6]=0; b[7]=0;
            kf[t] = a; qf[t] = b;
        }
        // S[m][q] tiles: C row = m local (lgrp*4+r), col = q local (lrow)
        f32x4 s[3][3];
        #pragma unroll
        for (int qt = 0; qt < 3; ++qt)
            #pragma unroll
            for (int mt = 0; mt < 3; ++mt)
                s[qt][mt] = __builtin_amdgcn_mfma_f32_16x16x32_bf16(kf[mt], qf[qt], (f32x4)0.0f, 0, 0, 0);

        // relative-position bias (rpe_t[h][.] : lanes spread over 23 banks)
        #pragma unroll
        for (int qt = 0; qt < 3; ++qt) {
            int q  = qt * 16 + lrow;
            int gx = gcl[q][0], gy = gcl[q][1], gz = gcl[q][2];
            #pragma unroll
            for (int mt = 0; mt < 3; ++mt)
                #pragma unroll
                for (int r = 0; r < 4; ++r) {
                    int m  = mt * 16 + lgrp * 4 + r;
                    int rx = gx - gcl[m][0];
                    int ry = gy - gcl[m][1];
                    int rz = gz - gcl[m][2];
                    rx = rx < -POS_BND ? -POS_BND : (rx > POS_BND ? POS_BND : rx);
                    ry = ry < -POS_BND ? -POS_BND : (ry > POS_BND ? POS_BND : ry);
                    rz = rz < -POS_BND ? -POS_BND : (rz > POS_BND ? POS_BND : rz);
                    s[qt][mt][r] += rbase[rx + POS_BND]
                                  + rbase[ry + POS_BND + RPE_NUM]
                                  + rbase[rz + POS_BND + 2 * RPE_NUM];
                }
        }

        // softmax over m (12 local + cross-lane l^16, l^32)
        #pragma unroll
        for (int qt = 0; qt < 3; ++qt) {
            float mx = -1e30f;
            #pragma unroll
            for (int mt = 0; mt < 3; ++mt)
                #pragma unroll
                for (int r = 0; r < 4; ++r) mx = fmaxf(mx, s[qt][mt][r]);
            mx = fmaxf(mx, __shfl_xor(mx, 16));
            mx = fmaxf(mx, __shfl_xor(mx, 32));
            float sum = 0.f;
            #pragma unroll
            for (int mt = 0; mt < 3; ++mt)
                #pragma unroll
                for (int r = 0; r < 4; ++r) {
                    float e = __expf(s[qt][mt][r] - mx);
                    s[qt][mt][r] = e;
                    sum += e;
                }
            sum += __shfl_xor(sum, 16);
            sum += __shfl_xor(sum, 32);
            float inv = 1.0f / sum;
            #pragma unroll
            for (int mt = 0; mt < 3; ++mt)
                #pragma unroll
                for (int r = 0; r < 4; ++r) s[qt][mt][r] *= inv;
        }

        // V B-frags: k-slot map {j0-3: m=ms*32+lgrp*4+j, j4-7: +16} matching P regs
        short8v vb0, vb1;
        {
            int base = VOFF + h * 1536 + lrow * 96 + (((lgrp ^ (lrow >> 2)) & 3)) * 8;
            short4v x0 = *(const short4v*)(uni + base);
            short4v x1 = *(const short4v*)(uni + base + 32);
            short4v x2 = *(const short4v*)(uni + base + 64);
            vb0[0]=x0[0]; vb0[1]=x0[1]; vb0[2]=x0[2]; vb0[3]=x0[3];
            vb0[4]=x1[0]; vb0[5]=x1[1]; vb0[6]=x1[2]; vb0[7]=x1[3];
            vb1[0]=x2[0]; vb1[1]=x2[1]; vb1[2]=x2[2]; vb1[3]=x2[3];
            vb1[4]=0; vb1[5]=0; vb1[6]=0; vb1[7]=0;
        }
        // PV: P regs are already A-fragments under the same k-slot map
        #pragma unroll
        for (int qt = 0; qt < 3; ++qt) {
            short8v pa0, pa1;
            #pragma unroll
            for (int j = 0; j < 4; ++j) {
                pa0[j]     = (short)bf16r(s[qt][0][j]);
                pa0[4 + j] = (short)bf16r(s[qt][1][j]);
                pa1[j]     = (short)bf16r(s[qt][2][j]);
                pa1[4 + j] = 0;
            }
            f32x4 o = __builtin_amdgcn_mfma_f32_16x16x32_bf16(pa0, vb0, (f32x4)0.0f, 0, 0, 0);
            o = __builtin_amdgcn_mfma_f32_16x16x32_bf16(pa1, vb1, o, 0, 0, 0);
            oall[qt] = o;
        }
    }
    __syncthreads();   // all qkv reads done; region becomes aoH/aoL

    // ---- write attention output hi/lo bf16 tile (same layout/swizzle as feat) ----
    {
        int c = wid * 16 + lrow;     // output column = h*16 + d
        #pragma unroll
        for (int qt = 0; qt < 3; ++qt)
            #pragma unroll
            for (int r = 0; r < 4; ++r) {
                int q = qt * 16 + lgrp * 4 + r; // output row
                float x = oall[qt][r];
                unsigned u = __float_as_uint(x);
                unsigned short h16 = (unsigned short)(u >> 16);
                float lres = x - __uint_as_float(u & 0xffff0000u);
                unsigned short l16 = (unsigned short)(__float_as_uint(lres) >> 16);
                int addr = (q * 256 + c * 2) ^ ((q & 7) << 4);
                *(unsigned short*)(uni + addr)        = h16;
                *(unsigned short*)(uni + KOFF + addr) = l16;
            }
    }
    __syncthreads();

    // ---- proj GEMM: M=48, N=128 (1 nt/wave), split-A x split-B ----
    f32x4 pacc[3];
    #pragma unroll
    for (int i = 0; i < 3; ++i) pacc[i] = (f32x4)0.0f;

    #pragma unroll
    for (int ks = 0; ks < 4; ++ks) {
        short8v aH[3], aL[3];
        #pragma unroll
        for (int mt = 0; mt < 3; ++mt) {
            int row  = mt * 16 + lrow;
            int boff = (row * 256 + ks * 64 + lgrp * 16) ^ ((row & 7) << 4);
            aH[mt] = *(const short8v*)(uni + boff);
            aL[mt] = *(const short8v*)(uni + KOFF + boff);
        }
        int woff = 49152 + (wid * 16 + lrow) * CDIM + ks * 32 + lgrp * 8;
        short8v bH = *(const short8v*)&g_whi[woff];
        short8v bL = *(const short8v*)&g_wlo[woff];
        #pragma unroll
        for (int mt = 0; mt < 3; ++mt) {
            pacc[mt] = __builtin_amdgcn_mfma_f32_16x16x32_bf16(aH[mt], bH, pacc[mt], 0, 0, 0);
            pacc[mt] = __builtin_amdgcn_mfma_f32_16x16x32_bf16(aL[mt], bH, pacc[mt], 0, 0, 0);
            pacc[mt] = __builtin_amdgcn_mfma_f32_16x16x32_bf16(aH[mt], bL, pacc[mt], 0, 0, 0);
        }
    }

    // ---- scatter rows to out (+bias) ----
    {
        int c  = wid * 16 + lrow;
        float bp = b_proj[c];
        #pragma unroll
        for (int mt = 0; mt < 3; ++mt)
            #pragma unroll
            for (int r = 0; r < 4; ++r) {
                int row = mt * 16 + lgrp * 4 + r;
                out[(size_t)ord[row] * CDIM + c] = pacc[mt][r] + bp;
            }
    }
}

extern "C" void kernel_launch(void* const* d_in, const int* in_sizes, int n_in,
                              void* d_out, int out_size, void* d_ws, size_t ws_size,
                              hipStream_t stream) {
    const float* feat   = (const float*)d_in[0];
    const float* w_qkv  = (const float*)d_in[1];
    const float* b_qkv  = (const float*)d_in[2];
    const float* w_proj = (const float*)d_in[3];
    const float* b_proj = (const float*)d_in[4];
    const float* rpe    = (const float*)d_in[5];
    const int*   order  = (const int*)d_in[6];
    const int*   gc     = (const int*)d_in[8];
    float* out = (float*)d_out;

    prep_w<<<64, 256, 0, stream>>>(w_qkv, w_proj);
    fused_patch_attn<<<NP, 512, 0, stream>>>(feat, b_qkv, b_proj, rpe, order, gc, out);
}